// Round 4
// baseline (224.062 us; speedup 1.0000x reference)
//
#include <hip/hip_runtime.h>

#define WI 512
#define HI 512
#define WO 2048
#define HO 2048
#define NIMG 8
#define CCH 3
#define EPS 1e-8f
#define ROWS 4
#define PLANE (HI * WI)          // 262144 texels per src plane

// ===========================================================================
// Table kernel: per (image, output coord) 1-D bilinear entry {w0,w1,off0,off1}
// for both axes. Weights premultiplied by validity (zeros padding); y offsets
// premultiplied by WI. Offsets are CLAMPED to valid range, so gathering with
// them is always in-bounds (enables the branchless main kernel).
// ===========================================================================
__global__ void diffcomp_tables(const float* __restrict__ coor,
                                int4* __restrict__ xtab,
                                int4* __restrict__ ytab) {
    const int idx = blockIdx.x * 256 + threadIdx.x;    // [0, 2*NIMG*2048)
    const bool isY = idx >= NIMG * WO;
    const int rem = isY ? idx - NIMG * WO : idx;
    const int n   = rem >> 11;
    const int pos = rem & 2047;

    const float cx = coor[n * 4 + 0];
    const float cy = coor[n * 4 + 1];
    const float cw = coor[n * 4 + 2];
    const float ch = coor[n * 4 + 3];

    float a, t, INF;
    if (!isY) {
        const float x = (1.0f / (1.0f + expf(-cx))) * (float)WO;
        const float w = (1.0f / (1.0f + expf(-cw))) * (float)WO;
        a = (float)WO / (w + EPS);
        t = (2.0f / (float)WO) * ((float)WO * 0.5f - x) * a;
        INF = (float)WI;
    } else {
        const float y = (1.0f / (1.0f + expf(-cy))) * (float)HO;
        const float h = (1.0f / (1.0f + expf(-ch))) * (float)HO;
        a = (float)HO / (h + EPS);
        t = (2.0f / (float)HO) * ((float)HO * 0.5f - y) * a;
        INF = (float)HI;
    }

    const float s  = (2.0f * (float)pos + 1.0f) / 2048.0f - 1.0f;
    const float g  = a * s + t;
    const float ic = ((g + 1.0f) * INF - 1.0f) * 0.5f;
    const float f0 = floorf(ic);
    const float fr1 = ic - f0;
    const float fr0 = 1.0f - fr1;
    const float f1 = f0 + 1.0f;
    const float v0 = (f0 >= 0.0f && f0 < INF) ? 1.0f : 0.0f;
    const float v1 = (f1 >= 0.0f && f1 < INF) ? 1.0f : 0.0f;
    const float w0 = fr0 * v0;
    const float w1 = fr1 * v1;
    int c0 = (int)fminf(fmaxf(f0, 0.0f), INF - 1.0f);
    int c1 = (int)fminf(fmaxf(f1, 0.0f), INF - 1.0f);
    if (isY) { c0 *= WI; c1 *= WI; }

    int4 e;
    e.x = __float_as_int(w0);
    e.y = __float_as_int(w1);
    e.z = c0;
    e.w = c1;
    (isY ? ytab : xtab)[(n << 11) + pos] = e;
}

// ===========================================================================
// Transpose kernel: src [N,C,HI,WI] planar -> srcI [N,HI*WI] float4 (rgb0).
// ===========================================================================
__launch_bounds__(256)
__global__ void diffcomp_interleave(const float* __restrict__ src,
                                    float4* __restrict__ srcI) {
    const int idx = blockIdx.x * 256 + threadIdx.x;    // [0, NIMG*PLANE)
    const int n   = idx >> 18;
    const int rem = idx & (PLANE - 1);
    const float* p = src + n * (CCH * PLANE) + rem;
    float4 v;
    v.x = p[0 * PLANE];
    v.y = p[1 * PLANE];
    v.z = p[2 * PLANE];
    v.w = 0.0f;
    srcI[idx] = v;
}

// ===========================================================================
// Main kernel v4: BRANCHLESS. Every thread gathers all 8 images' 4 corners
// unconditionally (clamped offsets always valid); uncovered images blend with
// m==0 which is bit-exact identity (acc*1 + s*0; s finite). No divergence,
// no control-dependent load episodes, uniform work per block (no tail).
// bg/out use non-temporal access (stream-once) to keep L2 for src gathers.
// ===========================================================================
__launch_bounds__(256)
__global__ void diffcomp_main4(const float4* __restrict__ srcI,
                               const float* __restrict__ bg,
                               const int4* __restrict__ xtab,
                               const int4* __restrict__ ytab,
                               float* __restrict__ out) {
    __shared__ int4 ylds[ROWS * NIMG];

    const int tid = threadIdx.x;
    const int wo  = blockIdx.x * 256 + tid;
    const int ho0 = blockIdx.y * ROWS;

    if (tid < ROWS * NIMG) {
        const int r = tid >> 3;
        const int n = tid & 7;
        ylds[tid] = ytab[(n << 11) + ho0 + r];
    }

    float wx0[NIMG], wx1[NIMG], mxv[NIMG];
    int   ox0[NIMG], ox1[NIMG];
#pragma unroll
    for (int n = 0; n < NIMG; n++) {
        const int4 e = xtab[(n << 11) + wo];
        wx0[n] = __int_as_float(e.x);
        wx1[n] = __int_as_float(e.y);
        ox0[n] = e.z;
        ox1[n] = e.w;
        mxv[n] = wx0[n] + wx1[n];
    }

    __syncthreads();

    for (int r = 0; r < ROWS; r++) {
        const int ho  = ho0 + r;
        const int pix = ho * WO + wo;

        float acc0 = __builtin_nontemporal_load(&bg[0 * HO * WO + pix]);
        float acc1 = __builtin_nontemporal_load(&bg[1 * HO * WO + pix]);
        float acc2 = __builtin_nontemporal_load(&bg[2 * HO * WO + pix]);

#pragma unroll
        for (int n = 0; n < NIMG; n++) {
            const int4 ey = ylds[r * NIMG + n];
            const float wy0 = __int_as_float(ey.x);
            const float wy1 = __int_as_float(ey.y);
            const float m  = (wy0 + wy1) * mxv[n];
            const float om = 1.0f - m;

            const float4* p = srcI + (n << 18);
            const float4 v00 = p[ey.z + ox0[n]];
            const float4 v01 = p[ey.z + ox1[n]];
            const float4 v10 = p[ey.w + ox0[n]];
            const float4 v11 = p[ey.w + ox1[n]];

            const float s0 = (v00.x * wy0 + v10.x * wy1) * wx0[n]
                           + (v01.x * wy0 + v11.x * wy1) * wx1[n];
            const float s1 = (v00.y * wy0 + v10.y * wy1) * wx0[n]
                           + (v01.y * wy0 + v11.y * wy1) * wx1[n];
            const float s2 = (v00.z * wy0 + v10.z * wy1) * wx0[n]
                           + (v01.z * wy0 + v11.z * wy1) * wx1[n];

            acc0 = acc0 * om + s0 * m;
            acc1 = acc1 * om + s1 * m;
            acc2 = acc2 * om + s2 * m;
        }

        __builtin_nontemporal_store(acc0, &out[0 * HO * WO + pix]);
        __builtin_nontemporal_store(acc1, &out[1 * HO * WO + pix]);
        __builtin_nontemporal_store(acc2, &out[2 * HO * WO + pix]);
    }
}

// ===========================================================================
// Fallback main (planar src, branchy) if ws can't hold srcI.
// ===========================================================================
__launch_bounds__(256)
__global__ void diffcomp_main2(const float* __restrict__ src,
                               const float* __restrict__ bg,
                               const int4* __restrict__ xtab,
                               const int4* __restrict__ ytab,
                               float* __restrict__ out) {
    __shared__ int4 ylds[ROWS * NIMG];

    const int tid = threadIdx.x;
    const int wo  = blockIdx.x * 256 + tid;
    const int ho0 = blockIdx.y * ROWS;

    if (tid < ROWS * NIMG) {
        const int r = tid >> 3;
        const int n = tid & 7;
        ylds[tid] = ytab[(n << 11) + ho0 + r];
    }

    float wx0[NIMG], wx1[NIMG], mxv[NIMG];
    int   ox0[NIMG], ox1[NIMG];
#pragma unroll
    for (int n = 0; n < NIMG; n++) {
        const int4 e = xtab[(n << 11) + wo];
        wx0[n] = __int_as_float(e.x);
        wx1[n] = __int_as_float(e.y);
        ox0[n] = e.z;
        ox1[n] = e.w;
        mxv[n] = wx0[n] + wx1[n];
    }

    __syncthreads();

    for (int r = 0; r < ROWS; r++) {
        const int ho  = ho0 + r;
        const int pix = ho * WO + wo;

        float acc0 = bg[0 * HO * WO + pix];
        float acc1 = bg[1 * HO * WO + pix];
        float acc2 = bg[2 * HO * WO + pix];

#pragma unroll
        for (int n = 0; n < NIMG; n++) {
            const int4 ey = ylds[r * NIMG + n];
            const float wy0 = __int_as_float(ey.x);
            const float wy1 = __int_as_float(ey.y);
            const float m = (wy0 + wy1) * mxv[n];
            if (m > 0.0f) {
                const float* ib = src + n * (CCH * PLANE);
                const int o00 = ey.z + ox0[n];
                const int o01 = ey.z + ox1[n];
                const int o10 = ey.w + ox0[n];
                const int o11 = ey.w + ox1[n];
                const float om = 1.0f - m;
                float s[CCH];
#pragma unroll
                for (int c = 0; c < CCH; c++) {
                    const float* p = ib + c * PLANE;
                    const float v00 = p[o00], v01 = p[o01], v10 = p[o10], v11 = p[o11];
                    s[c] = (v00 * wy0 + v10 * wy1) * wx0[n]
                         + (v01 * wy0 + v11 * wy1) * wx1[n];
                }
                acc0 = acc0 * om + s[0] * m;
                acc1 = acc1 * om + s[1] * m;
                acc2 = acc2 * om + s[2] * m;
            }
        }

        out[0 * HO * WO + pix] = acc0;
        out[1 * HO * WO + pix] = acc1;
        out[2 * HO * WO + pix] = acc2;
    }
}

extern "C" void kernel_launch(void* const* d_in, const int* in_sizes, int n_in,
                              void* d_out, int out_size, void* d_ws, size_t ws_size,
                              hipStream_t stream) {
    const float* src  = (const float*)d_in[0];   // [8,3,512,512]
    const float* bg   = (const float*)d_in[1];   // [1,3,2048,2048]
    const float* coor = (const float*)d_in[2];   // [8,4]
    float* out = (float*)d_out;                  // [1,3,2048,2048]

    const size_t tab_bytes  = (size_t)2 * NIMG * 2048 * sizeof(int4);   // 512 KB
    const size_t srcI_bytes = (size_t)NIMG * PLANE * sizeof(float4);    // 33.5 MB

    if (ws_size >= tab_bytes + srcI_bytes) {
        int4*   xtab = (int4*)d_ws;
        int4*   ytab = xtab + NIMG * 2048;
        float4* srcI = (float4*)((char*)d_ws + tab_bytes);

        hipLaunchKernelGGL(diffcomp_tables, dim3(128), dim3(256), 0, stream,
                           coor, xtab, ytab);
        hipLaunchKernelGGL(diffcomp_interleave, dim3(NIMG * PLANE / 256), dim3(256),
                           0, stream, src, srcI);
        dim3 grid(WO / 256, HO / ROWS);
        hipLaunchKernelGGL(diffcomp_main4, grid, dim3(256), 0, stream,
                           srcI, bg, xtab, ytab, out);
    } else {
        int4* xtab = (int4*)d_ws;
        int4* ytab = xtab + NIMG * 2048;
        hipLaunchKernelGGL(diffcomp_tables, dim3(128), dim3(256), 0, stream,
                           coor, xtab, ytab);
        dim3 grid(WO / 256, HO / ROWS);
        hipLaunchKernelGGL(diffcomp_main2, grid, dim3(256), 0, stream,
                           src, bg, xtab, ytab, out);
    }
}

// Round 5
// 172.865 us; speedup vs baseline: 1.2962x; 1.2962x over previous
//
#include <hip/hip_runtime.h>

#define WI 512
#define HI 512
#define WO 2048
#define HO 2048
#define NIMG 8
#define CCH 3
#define EPS 1e-8f
#define PLANE (HI * WI)          // 262144 texels per src plane

// ===========================================================================
// Params kernel: per-image (a, tx, b, ty) from coor (32 expf total).
// ===========================================================================
__global__ void diffcomp_params(const float* __restrict__ coor,
                                float4* __restrict__ params) {
    int n = threadIdx.x;
    if (n < NIMG) {
        float cx = coor[n * 4 + 0];
        float cy = coor[n * 4 + 1];
        float cw = coor[n * 4 + 2];
        float ch = coor[n * 4 + 3];
        float x = (1.0f / (1.0f + expf(-cx))) * (float)WO;
        float y = (1.0f / (1.0f + expf(-cy))) * (float)HO;
        float w = (1.0f / (1.0f + expf(-cw))) * (float)WO;
        float h = (1.0f / (1.0f + expf(-ch))) * (float)HO;
        float a  = (float)WO / (w + EPS);
        float tx = (2.0f / (float)WO) * ((float)WO * 0.5f - x) * a;
        float b  = (float)HO / (h + EPS);
        float ty = (2.0f / (float)HO) * ((float)HO * 0.5f - y) * b;
        params[n] = make_float4(a, tx, b, ty);
    }
}

// ===========================================================================
// Transpose kernel: src [N,C,HI,WI] planar -> srcI [N,HI*WI] float4 (rgb0).
// Fully coalesced both sides.
// ===========================================================================
__launch_bounds__(256)
__global__ void diffcomp_interleave(const float* __restrict__ src,
                                    float4* __restrict__ srcI) {
    const int idx = blockIdx.x * 256 + threadIdx.x;    // [0, NIMG*PLANE)
    const int n   = idx >> 18;
    const int rem = idx & (PLANE - 1);
    const float* p = src + n * (CCH * PLANE) + rem;
    float4 v;
    v.x = p[0 * PLANE];
    v.y = p[1 * PLANE];
    v.z = p[2 * PLANE];
    v.w = 0.0f;
    srcI[idx] = v;
}

// ===========================================================================
// Main kernel v5: one block per output row. ZERO scattered global loads.
//  - per covered image (block-uniform branch): stage its 2 src rows into LDS
//    with coalesced dwordx4 loads, y-collapse in place (row-uniform weights,
//    reference op order), then per-pixel x-gather from LDS (2 ds_read_b128).
//  - images in original order, groups of 2 (32 KB LDS -> 4 blocks/CU).
//  - rows covered by nothing = coalesced bg->out copy.
// ===========================================================================
__launch_bounds__(256)
__global__ void diffcomp_main5(const float4* __restrict__ srcI,
                               const float* __restrict__ bg,
                               const float4* __restrict__ params,
                               float* __restrict__ out) {
    __shared__ float4 rows[2][2][WI];      // [slot][row01][x] = 32 KB

    const int tid = threadIdx.x;
    const int ho  = blockIdx.x;
    const float ys = (2.0f * (float)ho + 1.0f) / (float)HO - 1.0f;

    float4 P[NIMG];
#pragma unroll
    for (int n = 0; n < NIMG; n++) P[n] = params[n];

    // Coverage bitmask (uniform across the block).
    unsigned cov = 0u;
#pragma unroll
    for (int n = 0; n < NIMG; n++) {
        const float gy  = P[n].z * ys + P[n].w;
        const float iy  = ((gy + 1.0f) * (float)HI - 1.0f) * 0.5f;
        const float y0f = floorf(iy);
        const float fy1 = iy - y0f;
        const float fy0 = 1.0f - fy1;
        const float y1f = y0f + 1.0f;
        const float v0  = (y0f >= 0.0f && y0f < (float)HI) ? 1.0f : 0.0f;
        const float v1  = (y1f >= 0.0f && y1f < (float)HI) ? 1.0f : 0.0f;
        const float my  = fy0 * v0 + fy1 * v1;
        if (my > 0.0f) cov |= (1u << n);
    }

    // Background accumulators: 8 px per thread, stride 256 (coalesced).
    float acc[CCH][8];
#pragma unroll
    for (int c = 0; c < CCH; c++)
#pragma unroll
        for (int p = 0; p < 8; p++)
            acc[c][p] = bg[c * HO * WO + ho * WO + p * 256 + tid];

    while (cov) {
        int ns[2];
        int cnt = 1;
        ns[0] = (int)__builtin_ctz(cov); cov &= cov - 1u;
        if (cov) { ns[1] = (int)__builtin_ctz(cov); cov &= cov - 1u; cnt = 2; }

        __syncthreads();   // protect LDS from previous group's readers

        // ---- stage: coalesced global -> LDS ----
        for (int s = 0; s < cnt; s++) {
            const int n = ns[s];
            const float gy  = P[n].z * ys + P[n].w;
            const float iy  = ((gy + 1.0f) * (float)HI - 1.0f) * 0.5f;
            const float y0f = floorf(iy);
            const float y1f = y0f + 1.0f;
            const int y0o = ((int)fminf(fmaxf(y0f, 0.0f), (float)(HI - 1))) << 9;
            const int y1o = ((int)fminf(fmaxf(y1f, 0.0f), (float)(HI - 1))) << 9;
            const float4* ip = srcI + (n << 18);
#pragma unroll
            for (int j = 0; j < 2; j++) {
                const int idx = j * 256 + tid;
                rows[s][0][idx] = ip[y0o + idx];
                rows[s][1][idx] = ip[y1o + idx];
            }
        }
        __syncthreads();

        // ---- y-collapse in place (reference order: y-blend first) ----
        for (int s = 0; s < cnt; s++) {
            const int n = ns[s];
            const float gy  = P[n].z * ys + P[n].w;
            const float iy  = ((gy + 1.0f) * (float)HI - 1.0f) * 0.5f;
            const float y0f = floorf(iy);
            const float fy1 = iy - y0f;
            const float fy0 = 1.0f - fy1;
            const float y1f = y0f + 1.0f;
            const float v0  = (y0f >= 0.0f && y0f < (float)HI) ? 1.0f : 0.0f;
            const float v1  = (y1f >= 0.0f && y1f < (float)HI) ? 1.0f : 0.0f;
            const float w0  = fy0 * v0;
            const float w1  = fy1 * v1;
#pragma unroll
            for (int j = 0; j < 2; j++) {
                const int idx = j * 256 + tid;
                const float4 r0 = rows[s][0][idx];
                const float4 r1 = rows[s][1][idx];
                float4 rc;
                rc.x = r0.x * w0 + r1.x * w1;
                rc.y = r0.y * w0 + r1.y * w1;
                rc.z = r0.z * w0 + r1.z * w1;
                rc.w = 0.0f;
                rows[s][0][idx] = rc;
            }
        }
        __syncthreads();

        // ---- accumulate: per-pixel x-gather from LDS ----
        for (int s = 0; s < cnt; s++) {
            const int n = ns[s];
            const float gy  = P[n].z * ys + P[n].w;
            const float iy  = ((gy + 1.0f) * (float)HI - 1.0f) * 0.5f;
            const float y0f = floorf(iy);
            const float fy1 = iy - y0f;
            const float fy0 = 1.0f - fy1;
            const float y1f = y0f + 1.0f;
            const float v0y = (y0f >= 0.0f && y0f < (float)HI) ? 1.0f : 0.0f;
            const float v1y = (y1f >= 0.0f && y1f < (float)HI) ? 1.0f : 0.0f;
            const float my  = fy0 * v0y + fy1 * v1y;
            const float a   = P[n].x;
            const float tx  = P[n].y;
#pragma unroll
            for (int p = 0; p < 8; p++) {
                const int wo = p * 256 + tid;
                const float xs  = (2.0f * (float)wo + 1.0f) / (float)WO - 1.0f;
                const float gx  = a * xs + tx;
                const float ix  = ((gx + 1.0f) * (float)WI - 1.0f) * 0.5f;
                const float x0f = floorf(ix);
                const float fx1 = ix - x0f;
                const float fx0 = 1.0f - fx1;
                const float x1f = x0f + 1.0f;
                const float v0  = (x0f >= 0.0f && x0f < (float)WI) ? 1.0f : 0.0f;
                const float v1  = (x1f >= 0.0f && x1f < (float)WI) ? 1.0f : 0.0f;
                const float wx0 = fx0 * v0;
                const float wx1 = fx1 * v1;
                const int x0c = (int)fminf(fmaxf(x0f, 0.0f), (float)(WI - 1));
                const int x1c = (int)fminf(fmaxf(x1f, 0.0f), (float)(WI - 1));
                const float4 t0 = rows[s][0][x0c];
                const float4 t1 = rows[s][0][x1c];
                const float m  = my * (wx0 + wx1);
                const float om = 1.0f - m;
                const float s0 = t0.x * wx0 + t1.x * wx1;
                const float s1 = t0.y * wx0 + t1.y * wx1;
                const float s2 = t0.z * wx0 + t1.z * wx1;
                acc[0][p] = acc[0][p] * om + s0 * m;
                acc[1][p] = acc[1][p] * om + s1 * m;
                acc[2][p] = acc[2][p] * om + s2 * m;
            }
        }
    }

#pragma unroll
    for (int c = 0; c < CCH; c++)
#pragma unroll
        for (int p = 0; p < 8; p++)
            out[c * HO * WO + ho * WO + p * 256 + tid] = acc[c][p];
}

// ===========================================================================
// Fallback main (round-1 structure: params only, branchy scalar gathers).
// ===========================================================================
__launch_bounds__(256)
__global__ void diffcomp_main(const float* __restrict__ src,
                              const float* __restrict__ bg,
                              const float4* __restrict__ params,
                              float* __restrict__ out) {
    const int wo  = blockIdx.x * 256 + threadIdx.x;
    const int ho0 = blockIdx.y * 8;

    float4 P[NIMG];
#pragma unroll
    for (int n = 0; n < NIMG; n++) P[n] = params[n];

    float wxv0[NIMG], wxv1[NIMG], mx[NIMG];
    int   x0c[NIMG], x1c[NIMG];
    const float xs = (2.0f * (float)wo + 1.0f) / (float)WO - 1.0f;
#pragma unroll
    for (int n = 0; n < NIMG; n++) {
        float a  = P[n].x, tx = P[n].y;
        float gx = a * xs + tx;
        float ix = (((gx + 1.0f) * (float)WI) - 1.0f) * 0.5f;
        float x0f = floorf(ix);
        float wx1 = ix - x0f;
        float wx0 = 1.0f - wx1;
        float x1f = x0f + 1.0f;
        float vx0 = (x0f >= 0.0f && x0f < (float)WI) ? 1.0f : 0.0f;
        float vx1 = (x1f >= 0.0f && x1f < (float)WI) ? 1.0f : 0.0f;
        wxv0[n] = wx0 * vx0;
        wxv1[n] = wx1 * vx1;
        x0c[n] = (int)fminf(fmaxf(x0f, 0.0f), (float)(WI - 1));
        x1c[n] = (int)fminf(fmaxf(x1f, 0.0f), (float)(WI - 1));
        mx[n] = wxv0[n] + wxv1[n];
    }

    for (int r = 0; r < 8; r++) {
        const int ho = ho0 + r;
        const float ysr = (2.0f * (float)ho + 1.0f) / (float)HO - 1.0f;
        const int pix = ho * WO + wo;

        float acc0 = bg[0 * HO * WO + pix];
        float acc1 = bg[1 * HO * WO + pix];
        float acc2 = bg[2 * HO * WO + pix];

#pragma unroll
        for (int n = 0; n < NIMG; n++) {
            float b  = P[n].z, ty = P[n].w;
            float gy = b * ysr + ty;
            float iy = (((gy + 1.0f) * (float)HI) - 1.0f) * 0.5f;
            float y0f = floorf(iy);
            float wy1 = iy - y0f;
            float wy0 = 1.0f - wy1;
        float y1f = y0f + 1.0f;
        float vy0 = (y0f >= 0.0f && y0f < (float)HI) ? 1.0f : 0.0f;
        float vy1 = (y1f >= 0.0f && y1f < (float)HI) ? 1.0f : 0.0f;
        float wyv0 = wy0 * vy0;
        float wyv1 = wy1 * vy1;
        float m = (wyv0 + wyv1) * mx[n];
            if (m > 0.0f) {
                int y0i = (int)fminf(fmaxf(y0f, 0.0f), (float)(HI - 1));
                int y1i = (int)fminf(fmaxf(y1f, 0.0f), (float)(HI - 1));
                const float* ib = src + n * (CCH * PLANE);
                const int o00 = y0i * WI + x0c[n];
                const int o01 = y0i * WI + x1c[n];
                const int o10 = y1i * WI + x0c[n];
                const int o11 = y1i * WI + x1c[n];
                const float om = 1.0f - m;
                float sc[CCH];
#pragma unroll
                for (int c = 0; c < CCH; c++) {
                    const float* p = ib + c * PLANE;
                    const float v00 = p[o00], v01 = p[o01], v10 = p[o10], v11 = p[o11];
                    sc[c] = (v00 * wyv0 + v10 * wyv1) * wxv0[n]
                          + (v01 * wyv0 + v11 * wyv1) * wxv1[n];
                }
                acc0 = acc0 * om + sc[0] * m;
                acc1 = acc1 * om + sc[1] * m;
                acc2 = acc2 * om + sc[2] * m;
            }
        }

        out[0 * HO * WO + pix] = acc0;
        out[1 * HO * WO + pix] = acc1;
        out[2 * HO * WO + pix] = acc2;
    }
}

extern "C" void kernel_launch(void* const* d_in, const int* in_sizes, int n_in,
                              void* d_out, int out_size, void* d_ws, size_t ws_size,
                              hipStream_t stream) {
    const float* src  = (const float*)d_in[0];   // [8,3,512,512]
    const float* bg   = (const float*)d_in[1];   // [1,3,2048,2048]
    const float* coor = (const float*)d_in[2];   // [8,4]
    float* out = (float*)d_out;                  // [1,3,2048,2048]

    const size_t par_bytes  = NIMG * sizeof(float4);                  // 128 B
    const size_t srcI_bytes = (size_t)NIMG * PLANE * sizeof(float4);  // 33.5 MB

    float4* params = (float4*)d_ws;
    hipLaunchKernelGGL(diffcomp_params, dim3(1), dim3(64), 0, stream, coor, params);

    if (ws_size >= par_bytes + srcI_bytes + 256) {
        float4* srcI = (float4*)((char*)d_ws + 256);   // aligned past params
        hipLaunchKernelGGL(diffcomp_interleave, dim3(NIMG * PLANE / 256), dim3(256),
                           0, stream, src, srcI);
        hipLaunchKernelGGL(diffcomp_main5, dim3(HO), dim3(256), 0, stream,
                           srcI, bg, params, out);
    } else {
        dim3 grid(WO / 256, HO / 8);
        hipLaunchKernelGGL(diffcomp_main, grid, dim3(256), 0, stream,
                           src, bg, params, out);
    }
}

// Round 6
// 134.453 us; speedup vs baseline: 1.6665x; 1.2857x over previous
//
#include <hip/hip_runtime.h>

#define WI 512
#define HI 512
#define WO 2048
#define HO 2048
#define NIMG 8
#define CCH 3
#define EPS 1e-8f
#define PLANE (HI * WI)

// Per-image y-uniform quantities for output row at normalized coord ys.
__device__ __forceinline__ void ycalc(const float4 P, const float ys,
                                      float& wyv0, float& wyv1,
                                      int& y0o, int& y1o) {
    const float gy  = P.z * ys + P.w;
    const float iy  = ((gy + 1.0f) * (float)HI - 1.0f) * 0.5f;
    const float y0f = floorf(iy);
    const float fy1 = iy - y0f;
    const float fy0 = 1.0f - fy1;
    const float y1f = y0f + 1.0f;
    const float v0  = (y0f >= 0.0f && y0f < (float)HI) ? 1.0f : 0.0f;
    const float v1  = (y1f >= 0.0f && y1f < (float)HI) ? 1.0f : 0.0f;
    wyv0 = fy0 * v0;
    wyv1 = fy1 * v1;
    y0o = (int)fminf(fmaxf(y0f, 0.0f), (float)(HI - 1)) * WI;
    y1o = (int)fminf(fmaxf(y1f, 0.0f), (float)(HI - 1)) * WI;
}

// Stage image n's two src rows into dst[3][512], y-collapsed (reference's
// `rows` = img[y0c]*wyv0 + img[y1c]*wyv1). Threads 0..127, coalesced float4
// loads, conflict-free lane-consecutive b128 LDS writes.
__device__ __forceinline__ void stage_rows(float (*dst)[WI],
                                           const float* __restrict__ src,
                                           const int n,
                                           const float wyv0, const float wyv1,
                                           const int y0o, const int y1o,
                                           const int tid) {
    if (tid < 128) {
        const int x = tid << 2;
        const float* base = src + n * (CCH * PLANE);
#pragma unroll
        for (int c = 0; c < CCH; c++) {
            const float4 r0 = *(const float4*)(base + c * PLANE + y0o + x);
            const float4 r1 = *(const float4*)(base + c * PLANE + y1o + x);
            float4 rc;
            rc.x = r0.x * wyv0 + r1.x * wyv1;
            rc.y = r0.y * wyv0 + r1.y * wyv1;
            rc.z = r0.z * wyv0 + r1.z * wyv1;
            rc.w = r0.w * wyv0 + r1.w * wyv1;
            *(float4*)&dst[c][x] = rc;
        }
    }
}

// ===========================================================================
// Fused single kernel: one block per output row (ys uniform -> coverage
// branches are wave-uniform). Double-buffered LDS row staging, one barrier
// per covered image. acc[3][8] = 24 VGPR of persistent state; everything
// else recomputed from LDS params to avoid spills.
// ===========================================================================
__launch_bounds__(256)
__global__ void diffcomp_fused(const float* __restrict__ src,
                               const float* __restrict__ bg,
                               const float* __restrict__ coor,
                               float* __restrict__ out) {
    __shared__ float  cs[2][CCH][WI];   // y-collapsed rows, 2 slots = 12 KB
    __shared__ float4 prm[NIMG];        // (a, tx, b, ty)

    const int tid = threadIdx.x;
    const int ho  = (int)((blockIdx.x * 997u) & 2047u);  // balance swizzle

    if (tid < NIMG) {
        const float cx = coor[tid * 4 + 0];
        const float cy = coor[tid * 4 + 1];
        const float cw = coor[tid * 4 + 2];
        const float chh = coor[tid * 4 + 3];
        const float x = (1.0f / (1.0f + expf(-cx))) * (float)WO;
        const float y = (1.0f / (1.0f + expf(-cy))) * (float)HO;
        const float w = (1.0f / (1.0f + expf(-cw))) * (float)WO;
        const float h = (1.0f / (1.0f + expf(-chh))) * (float)HO;
        const float a  = (float)WO / (w + EPS);
        const float tx = (2.0f / (float)WO) * ((float)WO * 0.5f - x) * a;
        const float b  = (float)HO / (h + EPS);
        const float ty = (2.0f / (float)HO) * ((float)HO * 0.5f - y) * b;
        prm[tid] = make_float4(a, tx, b, ty);
    }
    __syncthreads();

    const float ys = (2.0f * (float)ho + 1.0f) / (float)HO - 1.0f;

    // Coverage bitmask (identical on every thread; branches are uniform).
    unsigned cov = 0u;
#pragma unroll
    for (int n = 0; n < NIMG; n++) {
        float w0, w1; int a0, a1;
        ycalc(prm[n], ys, w0, w1, a0, a1);
        if (w0 + w1 > 0.0f) cov |= (1u << n);
    }

    // Background accumulators: 8 consecutive px per thread (coalesced float4).
    const int rowbase = ho * WO + (tid << 3);
    float acc[CCH][8];
#pragma unroll
    for (int c = 0; c < CCH; c++) {
        const float4 b0 = *(const float4*)(bg + c * HO * WO + rowbase);
        const float4 b1 = *(const float4*)(bg + c * HO * WO + rowbase + 4);
        acc[c][0] = b0.x; acc[c][1] = b0.y; acc[c][2] = b0.z; acc[c][3] = b0.w;
        acc[c][4] = b1.x; acc[c][5] = b1.y; acc[c][6] = b1.z; acc[c][7] = b1.w;
    }

    if (cov) {
        int cur = (int)__builtin_ctz(cov);
        unsigned rest = cov & (cov - 1u);

        float4 Pc = prm[cur];
        float w0c, w1c; int y0c, y1c;
        ycalc(Pc, ys, w0c, w1c, y0c, y1c);
        float myc = w0c + w1c;
        stage_rows(cs[0], src, cur, w0c, w1c, y0c, y1c, tid);
        __syncthreads();

        int s = 0;
        while (true) {
            const int nxt = rest ? (int)__builtin_ctz(rest) : -1;
            float4 Pn; float mynxt = 0.0f;
            if (nxt >= 0) {
                Pn = prm[nxt];
                float w0n, w1n; int a0, a1;
                ycalc(Pn, ys, w0n, w1n, a0, a1);
                mynxt = w0n + w1n;
                stage_rows(cs[s ^ 1], src, nxt, w0n, w1n, a0, a1, tid);
            }

            // ---- blend image `cur` from slot s ----
            const float a  = Pc.x;
            const float tx = Pc.y;
#pragma unroll
            for (int p = 0; p < 8; p++) {
                const int wo = (tid << 3) + p;
                const float xs  = (2.0f * (float)wo + 1.0f) / (float)WO - 1.0f;
                const float gx  = a * xs + tx;
                const float ix  = ((gx + 1.0f) * (float)WI - 1.0f) * 0.5f;
                const float x0f = floorf(ix);
                const float fx1 = ix - x0f;
                const float fx0 = 1.0f - fx1;
                const float vx0 = (x0f >= 0.0f && x0f < (float)WI) ? 1.0f : 0.0f;
                const float vx1 = (x0f >= -1.0f && x0f < (float)(WI - 1)) ? 1.0f : 0.0f;
                const float wxv0 = fx0 * vx0;
                const float wxv1 = fx1 * vx1;
                const int bse = (int)fminf(fmaxf(x0f, 0.0f), (float)(WI - 2));
                const int x0i = (int)fminf(fmaxf(x0f, 0.0f), (float)(WI - 1));
                const int x1i = (int)fminf(fmaxf(x0f + 1.0f, 0.0f), (float)(WI - 1));
                const bool hi0 = (x0i != bse);   // corner0 sits at bse+1
                const bool hi1 = (x1i != bse);   // corner1 sits at bse+1
                const float m  = myc * (wxv0 + wxv1);
                const float om = 1.0f - m;
#pragma unroll
                for (int c = 0; c < CCH; c++) {
                    const float qa = cs[s][c][bse];
                    const float qb = cs[s][c][bse + 1];
                    const float v0 = hi0 ? qb : qa;
                    const float v1 = hi1 ? qb : qa;
                    const float sc = v0 * wxv0 + v1 * wxv1;
                    acc[c][p] = acc[c][p] * om + sc * m;
                }
            }

            __syncthreads();
            if (nxt < 0) break;
            Pc = Pn; myc = mynxt;
            rest &= rest - 1u;
            s ^= 1;
        }
    }

#pragma unroll
    for (int c = 0; c < CCH; c++) {
        const float4 o0 = make_float4(acc[c][0], acc[c][1], acc[c][2], acc[c][3]);
        const float4 o1 = make_float4(acc[c][4], acc[c][5], acc[c][6], acc[c][7]);
        *(float4*)(out + c * HO * WO + rowbase)     = o0;
        *(float4*)(out + c * HO * WO + rowbase + 4) = o1;
    }
}

extern "C" void kernel_launch(void* const* d_in, const int* in_sizes, int n_in,
                              void* d_out, int out_size, void* d_ws, size_t ws_size,
                              hipStream_t stream) {
    const float* src  = (const float*)d_in[0];   // [8,3,512,512]
    const float* bg   = (const float*)d_in[1];   // [1,3,2048,2048]
    const float* coor = (const float*)d_in[2];   // [8,4]
    float* out = (float*)d_out;                  // [1,3,2048,2048]
    (void)d_ws; (void)ws_size;

    hipLaunchKernelGGL(diffcomp_fused, dim3(HO), dim3(256), 0, stream,
                       src, bg, coor, out);
}